// Round 4
// baseline (537.389 us; speedup 1.0000x reference)
//
#include <hip/hip_runtime.h>
#include <hip/hip_fp16.h>

typedef _Float16 f16x8 __attribute__((ext_vector_type(8)));
typedef float f32x4 __attribute__((ext_vector_type(4)));

// Workspace layout (bytes):
//   qv     [0,       65536)   : 32x512 f32   q = query @ Wq^T
//   bfrag  [65536,   589824)  : 512x512 f16  Wk^T in MFMA-fragment-major layout
//   scores [589824,  851968)  : 32x2048 f32  pre-softmax scores
//   vpart  [851968, 2949120)  : 1024x512 f32 per-tile unnormalized attn@keys
//   stats  [2949120, 2957312) : 1024x2 f32   per-tile (m, l)
#define WS_QV 0
#define WS_BF 65536
#define WS_SC 589824
#define WS_VP 851968
#define WS_ST 2949120

// ---------------- P: qv = query@Wq^T (fp32) + prepack Wk -> fp16 fragment layout ----
__global__ __launch_bounds__(256) void prep_kernel(
    const float* __restrict__ query, const float* __restrict__ Wq,
    const float* __restrict__ Wk, float* __restrict__ qv,
    _Float16* __restrict__ bfrag) {
  const int blk = blockIdx.x, tid = threadIdx.x;
  if (blk < 64) {
    const int b = blk >> 1;
    const int h = ((blk & 1) << 8) + tid;
    const float4* qr = (const float4*)(query + (size_t)b * 512);
    const float4* wr = (const float4*)(Wq + (size_t)h * 512);
    float acc = 0.f;
#pragma unroll 8
    for (int i = 0; i < 128; ++i) {
      float4 a = qr[i], w = wr[i];
      acc += a.x * w.x + a.y * w.y + a.z * w.z + a.w * w.w;
    }
    qv[b * 512 + h] = acc;
  } else {
    // B-fragment for mfma_f32_16x16x32_f16: unit u = nt*16 + ks
    // lane l supplies B[k = 32*ks + 8*(l>>4)+e][col = 16*nt + (l&15)] = Wk[col][k]
    const int u = (blk - 64) * 4 + (tid >> 6);
    const int l = tid & 63;
    const int col = ((u >> 4) << 4) + (l & 15);
    const int k0 = ((u & 15) << 5) + ((l >> 4) << 3);
    const float4* src = (const float4*)(Wk + (size_t)col * 512 + k0);
    float4 x = src[0], y = src[1];
    f16x8 v;
    v[0] = (_Float16)x.x; v[1] = (_Float16)x.y;
    v[2] = (_Float16)x.z; v[3] = (_Float16)x.w;
    v[4] = (_Float16)y.x; v[5] = (_Float16)y.y;
    v[6] = (_Float16)y.z; v[7] = (_Float16)y.w;
    *(f16x8*)(bfrag + (size_t)u * 512 + l * 8) = v;
  }
}

// ---------------- F: fused keys@Wk^T -> tanh -> scores -> tile softmax -> attn@keys
// Grid 1024: wg = 64 rows of one batch. 4 waves; wave w owns h-cols [128w, 128w+128).
// LDS: only a 2 x 16 KiB chunk double-buffer (64 rows x 128 k fp16, XOR-swizzled)
// -> ~34 KB/block -> 4 blocks/CU; latency hiding via independent-block TLP.
// V-phase re-reads keys from global (L3-hot) in fp32.
__global__ __launch_bounds__(256, 4) void fused_kernel(
    const float* __restrict__ keys, const _Float16* __restrict__ bfrag,
    const float* __restrict__ qv, const float* __restrict__ w_att,
    float* __restrict__ scores, float* __restrict__ vpart,
    float* __restrict__ stats) {
  __shared__ __align__(128) unsigned char lds[32768];   // 2 x (64 x 128 fp16)
  __shared__ float spart[256];
  __shared__ float pb[64];
  __shared__ float pb2[64];
  const int tid = threadIdx.x, w = tid >> 6, l = tid & 63;
  const int wg = blockIdx.x;
  const int row0 = wg * 64;
  const int b = row0 >> 11;

  // staging: thread owns row sr, 32 floats at chunk-local col scb*32
  const int sr = tid >> 2, scb = tid & 3;
  const float* gsrc = keys + (size_t)(row0 + sr) * 512 + scb * 32;
  const int wbase = sr * 256 + scb * 64;      // byte offset within chunk buffer
  const int wswz = (sr & 7) << 4;

  float4 stg[8];
#pragma unroll
  for (int j = 0; j < 8; ++j) stg[j] = ((const float4*)gsrc)[j];
  {
    unsigned char* dbuf = lds;                // buffer 0
#pragma unroll
    for (int j2 = 0; j2 < 4; ++j2) {
      float4 x = stg[2 * j2], y = stg[2 * j2 + 1];
      f16x8 h;
      h[0] = (_Float16)x.x; h[1] = (_Float16)x.y;
      h[2] = (_Float16)x.z; h[3] = (_Float16)x.w;
      h[4] = (_Float16)y.x; h[5] = (_Float16)y.y;
      h[6] = (_Float16)y.z; h[7] = (_Float16)y.w;
      *(f16x8*)(dbuf + ((wbase + j2 * 16) ^ wswz)) = h;
    }
  }
  __syncthreads();

  f32x4 acc[4][8];
#pragma unroll
  for (int mt = 0; mt < 4; ++mt)
#pragma unroll
    for (int nt = 0; nt < 8; ++nt) {
      acc[mt][nt][0] = 0.f; acc[mt][nt][1] = 0.f;
      acc[mt][nt][2] = 0.f; acc[mt][nt][3] = 0.f;
    }

  const int aswz = (l & 7) << 4;
  const int arow = (l & 15) * 256;
  const int acol = (l >> 4) << 4;

#pragma unroll
  for (int c = 0; c < 4; ++c) {
    // ---- issue global loads for chunk c+1 (in flight during compute)
    if (c < 3) {
      const float4* g = (const float4*)(gsrc + (c + 1) * 128);
#pragma unroll
      for (int j = 0; j < 8; ++j) stg[j] = g[j];
    }
    __builtin_amdgcn_sched_barrier(0);

    // ---- compute chunk c from buf[c&1]
    const unsigned char* buf = lds + (c & 1) * 16384;
#pragma unroll
    for (int kl = 0; kl < 4; ++kl) {
      const int ks = c * 4 + kl;
      f16x8 bf[8];
#pragma unroll
      for (int nt = 0; nt < 8; ++nt) {
        int u = (w * 8 + nt) * 16 + ks;
        bf[nt] = *(const f16x8*)(bfrag + (size_t)u * 512 + l * 8);
      }
      f16x8 af[4];
#pragma unroll
      for (int mt = 0; mt < 4; ++mt) {
        int byte = mt * 4096 + arow + ((kl * 64 + acol) ^ aswz);
        af[mt] = *(const f16x8*)(buf + byte);
      }
#pragma unroll
      for (int mt = 0; mt < 4; ++mt)
#pragma unroll
        for (int nt = 0; nt < 8; ++nt)
          acc[mt][nt] = __builtin_amdgcn_mfma_f32_16x16x32_f16(
              af[mt], bf[nt], acc[mt][nt], 0, 0, 0);
    }
    __builtin_amdgcn_sched_barrier(0);

    // ---- cvt + write chunk c+1 into buf[(c+1)&1]
    if (c < 3) {
      unsigned char* dbuf = lds + ((c + 1) & 1) * 16384;
#pragma unroll
      for (int j2 = 0; j2 < 4; ++j2) {
        float4 x = stg[2 * j2], y = stg[2 * j2 + 1];
        f16x8 h;
        h[0] = (_Float16)x.x; h[1] = (_Float16)x.y;
        h[2] = (_Float16)x.z; h[3] = (_Float16)x.w;
        h[4] = (_Float16)y.x; h[5] = (_Float16)y.y;
        h[6] = (_Float16)y.z; h[7] = (_Float16)y.w;
        *(f16x8*)(dbuf + ((wbase + j2 * 16) ^ wswz)) = h;
      }
      __syncthreads();
    }
  }

  // ---- epilogue: tanh(qv + k) * w_att, reduce over h -> per-row scores
  float rs[16];
#pragma unroll
  for (int i = 0; i < 16; ++i) rs[i] = 0.f;
  const int hb = w * 128;
#pragma unroll
  for (int nt = 0; nt < 8; ++nt) {
    const int h = hb + nt * 16 + (l & 15);
    const float q = qv[b * 512 + h];
    const float wa = w_att[h];
#pragma unroll
    for (int mt = 0; mt < 4; ++mt)
#pragma unroll
      for (int r = 0; r < 4; ++r) {
        float x = q + acc[mt][nt][r];
        float e = __expf(x + x);
        float t = 1.f - __fdividef(2.f, e + 1.f);
        rs[mt * 4 + r] = __builtin_fmaf(t, wa, rs[mt * 4 + r]);
      }
  }
#pragma unroll
  for (int st = 1; st <= 8; st <<= 1)
#pragma unroll
    for (int i = 0; i < 16; ++i)
      rs[i] += __shfl_xor(rs[i], st, 64);

  __syncthreads();     // chunk buffers dead; LDS arrays reused below
  {
    const int idx = l & 15;
    float v = rs[0];
#pragma unroll
    for (int i = 1; i < 16; ++i) v = (idx == i) ? rs[i] : v;
    const int rrow = ((idx >> 2) << 4) + ((l >> 4) << 2) + (idx & 3);
    spart[w * 64 + rrow] = v;
  }
  __syncthreads();
  if (tid < 64) {
    float s = spart[tid] + spart[64 + tid] + spart[128 + tid] + spart[192 + tid];
    scores[row0 + tid] = s;
    pb[tid] = s;
  }
  __syncthreads();

  // ---- tile softmax stats
  float m = -1e30f;
#pragma unroll 16
  for (int r = 0; r < 64; ++r) m = fmaxf(m, pb[r]);      // broadcast reads
  if (tid < 64) pb2[tid] = __expf(pb[tid] - m);
  __syncthreads();

  // ---- V-partial: vpart[wg][d] = sum_r pb2[r] * keys[row0+r][d]  (fp32, L3-hot)
  {
    float a0 = 0.f, a1 = 0.f;
    const float* kb = keys + (size_t)row0 * 512 + 2 * tid;
#pragma unroll 8
    for (int r = 0; r < 64; ++r) {
      float2 kv = *(const float2*)(kb + (size_t)r * 512);
      float p = pb2[r];
      a0 = __builtin_fmaf(p, kv.x, a0);
      a1 = __builtin_fmaf(p, kv.y, a1);
    }
    float2 o; o.x = a0; o.y = a1;
    *(float2*)(vpart + (size_t)wg * 512 + 2 * tid) = o;
  }
  if (tid == 0) {
    float lsum = 0.f;
#pragma unroll 16
    for (int r = 0; r < 64; ++r) lsum += pb2[r];
    stats[wg * 2] = m;
    stats[wg * 2 + 1] = lsum;
  }
}

// ---------------- C: combine 32 tiles per batch -> out, attn ----------------------
__global__ __launch_bounds__(256) void combine_kernel(
    const float* __restrict__ vpart, const float* __restrict__ stats,
    const float* __restrict__ scores, float* __restrict__ out,
    float* __restrict__ attn) {
  const int blk = blockIdx.x, tid = threadIdx.x;
  const int b = blk & 31;
  float mt[32], lt[32];
  float M = -1e30f;
#pragma unroll
  for (int t = 0; t < 32; ++t) {
    mt[t] = stats[(b * 32 + t) * 2];
    lt[t] = stats[(b * 32 + t) * 2 + 1];
    M = fmaxf(M, mt[t]);
  }
  float L = 0.f;
#pragma unroll
  for (int t = 0; t < 32; ++t) L += __expf(mt[t] - M) * lt[t];
  const float rinv = 1.f / L;

  if (blk < 32) {
    const int d0 = 2 * tid;
    float a0 = 0.f, a1 = 0.f;
#pragma unroll
    for (int t = 0; t < 32; ++t) {
      float wgt = __expf(mt[t] - M);
      float2 vp = *(const float2*)(vpart + ((size_t)(b * 32 + t)) * 512 + d0);
      a0 = __builtin_fmaf(wgt, vp.x, a0);
      a1 = __builtin_fmaf(wgt, vp.y, a1);
    }
    out[b * 512 + d0] = a0 * rinv;
    out[b * 512 + d0 + 1] = a1 * rinv;
  } else {
#pragma unroll
    for (int j = 0; j < 8; ++j) {
      int s = j * 256 + tid;
      attn[(size_t)b * 2048 + s] = __expf(scores[(size_t)b * 2048 + s] - M) * rinv;
    }
  }
}

extern "C" void kernel_launch(void* const* d_in, const int* in_sizes, int n_in,
                              void* d_out, int out_size, void* d_ws, size_t ws_size,
                              hipStream_t stream) {
  const float* query = (const float*)d_in[0];
  const float* keys  = (const float*)d_in[1];
  const float* Wq    = (const float*)d_in[2];
  const float* Wk    = (const float*)d_in[3];
  const float* w_att = (const float*)d_in[4];
  float* out  = (float*)d_out;                  // [32,512]
  float* attn = out + 16384;                    // [32,2048]
  char* ws = (char*)d_ws;
  float*    qv     = (float*)(ws + WS_QV);
  _Float16* bfrag  = (_Float16*)(ws + WS_BF);
  float*    scores = (float*)(ws + WS_SC);
  float*    vpart  = (float*)(ws + WS_VP);
  float*    stats  = (float*)(ws + WS_ST);

  prep_kernel<<<192, 256, 0, stream>>>(query, Wq, Wk, qv, bfrag);
  fused_kernel<<<1024, 256, 0, stream>>>(keys, bfrag, qv, w_att, scores, vpart, stats);
  combine_kernel<<<64, 256, 0, stream>>>(vpart, stats, scores, out, attn);
}

// Round 5
// 114.915 us; speedup vs baseline: 4.6764x; 4.6764x over previous
//
#include <hip/hip_runtime.h>
#include <hip/hip_fp16.h>

typedef _Float16 f16x8 __attribute__((ext_vector_type(8)));
typedef _Float16 f16x2 __attribute__((ext_vector_type(2)));
typedef float f32x4 __attribute__((ext_vector_type(4)));

// Workspace layout (bytes):
//   qv     [0,       65536)   : 32x512 f32   q = query @ Wq^T
//   bfrag  [65536,   589824)  : 512x512 f16  Wk^T in MFMA-fragment-major layout
//   scores [589824,  851968)  : 32x2048 f32  pre-softmax scores
//   vpart  [851968, 2949120)  : 2048x512 f16 per-tile unnormalized attn@keys
//   stats  [2949120, 2965504) : 2048x2 f32   per-tile (m, l)
#define WS_QV 0
#define WS_BF 65536
#define WS_SC 589824
#define WS_VP 851968
#define WS_ST 2949120

// ---------------- P: qv = query@Wq^T (fp32) + prepack Wk -> fp16 fragment layout ----
__global__ __launch_bounds__(256) void prep_kernel(
    const float* __restrict__ query, const float* __restrict__ Wq,
    const float* __restrict__ Wk, float* __restrict__ qv,
    _Float16* __restrict__ bfrag) {
  const int blk = blockIdx.x, tid = threadIdx.x;
  if (blk < 64) {
    const int b = blk >> 1;
    const int h = ((blk & 1) << 8) + tid;
    const float4* qr = (const float4*)(query + (size_t)b * 512);
    const float4* wr = (const float4*)(Wq + (size_t)h * 512);
    float acc = 0.f;
#pragma unroll 8
    for (int i = 0; i < 128; ++i) {
      float4 a = qr[i], w = wr[i];
      acc += a.x * w.x + a.y * w.y + a.z * w.z + a.w * w.w;
    }
    qv[b * 512 + h] = acc;
  } else {
    // B-fragment for mfma_f32_16x16x32_f16: unit u = nt*16 + ks
    // lane l supplies B[k = 32*ks + 8*(l>>4)+e][col = 16*nt + (l&15)] = Wk[col][k]
    const int u = (blk - 64) * 4 + (tid >> 6);
    const int l = tid & 63;
    const int col = ((u >> 4) << 4) + (l & 15);
    const int k0 = ((u & 15) << 5) + ((l >> 4) << 3);
    const float4* src = (const float4*)(Wk + (size_t)col * 512 + k0);
    float4 x = src[0], y = src[1];
    f16x8 v;
    v[0] = (_Float16)x.x; v[1] = (_Float16)x.y;
    v[2] = (_Float16)x.z; v[3] = (_Float16)x.w;
    v[4] = (_Float16)y.x; v[5] = (_Float16)y.y;
    v[6] = (_Float16)y.z; v[7] = (_Float16)y.w;
    *(f16x8*)(bfrag + (size_t)u * 512 + l * 8) = v;
  }
}

// ---------------- F: fused keys@Wk^T -> tanh -> scores -> tile softmax -> attn@keys
// Grid 2048: wg = 32 rows. 4 waves; wave w owns h-cols [128w, 128w+128).
// acc[2][8] = 64 regs/lane -> target ~130 total regs -> 3-4 blocks/CU resident.
// LDS: 2 x 8 KiB chunk double-buffer (32 rows x 128 k fp16, XOR-swizzled).
__global__ __launch_bounds__(256) void fused_kernel(
    const float* __restrict__ keys, const _Float16* __restrict__ bfrag,
    const float* __restrict__ qv, const float* __restrict__ w_att,
    float* __restrict__ scores, _Float16* __restrict__ vpart,
    float* __restrict__ stats) {
  __shared__ __align__(128) unsigned char lds[16384];   // 2 x (32 x 128 fp16)
  __shared__ float spart[128];
  __shared__ float pb[32];
  __shared__ float pb2[32];
  const int tid = threadIdx.x, w = tid >> 6, l = tid & 63;
  const int wg = blockIdx.x;
  const int row0 = wg * 32;
  const int b = row0 >> 11;

  // staging: thread owns row sr, 16 floats at chunk-local col scb*16
  const int sr = tid >> 3, scb = tid & 7;
  const float* gsrc = keys + (size_t)(row0 + sr) * 512 + scb * 16;
  const int wbase = sr * 256 + scb * 32;      // byte offset within chunk buffer
  const int wswz = (sr & 7) << 4;

  float4 stg[4];
#pragma unroll
  for (int j = 0; j < 4; ++j) stg[j] = ((const float4*)gsrc)[j];
  {
    unsigned char* dbuf = lds;                // buffer 0
#pragma unroll
    for (int j2 = 0; j2 < 2; ++j2) {
      float4 x = stg[2 * j2], y = stg[2 * j2 + 1];
      f16x8 h;
      h[0] = (_Float16)x.x; h[1] = (_Float16)x.y;
      h[2] = (_Float16)x.z; h[3] = (_Float16)x.w;
      h[4] = (_Float16)y.x; h[5] = (_Float16)y.y;
      h[6] = (_Float16)y.z; h[7] = (_Float16)y.w;
      *(f16x8*)(dbuf + ((wbase + j2 * 16) ^ wswz)) = h;
    }
  }
  __syncthreads();

  f32x4 acc[2][8];
#pragma unroll
  for (int mt = 0; mt < 2; ++mt)
#pragma unroll
    for (int nt = 0; nt < 8; ++nt) {
      acc[mt][nt][0] = 0.f; acc[mt][nt][1] = 0.f;
      acc[mt][nt][2] = 0.f; acc[mt][nt][3] = 0.f;
    }

  const int aswz = (l & 7) << 4;
  const int arow = (l & 15) * 256;
  const int acol = (l >> 4) << 4;

#pragma unroll
  for (int c = 0; c < 4; ++c) {
    // ---- issue global loads for chunk c+1 (in flight during compute)
    if (c < 3) {
      const float4* g = (const float4*)(gsrc + (c + 1) * 128);
#pragma unroll
      for (int j = 0; j < 4; ++j) stg[j] = g[j];
    }
    __builtin_amdgcn_sched_barrier(0);

    // ---- compute chunk c from buf[c&1]
    const unsigned char* buf = lds + (c & 1) * 8192;
#pragma unroll
    for (int kl = 0; kl < 4; ++kl) {
      const int ks = c * 4 + kl;
      f16x8 af[2];
#pragma unroll
      for (int mt = 0; mt < 2; ++mt) {
        int byte = mt * 4096 + arow + ((kl * 64 + acol) ^ aswz);
        af[mt] = *(const f16x8*)(buf + byte);
      }
      // two half-groups of 4 nt to cap live bf regs at 16
#pragma unroll
      for (int nh = 0; nh < 2; ++nh) {
        f16x8 bf[4];
#pragma unroll
        for (int n4 = 0; n4 < 4; ++n4) {
          int u = (w * 8 + nh * 4 + n4) * 16 + ks;
          bf[n4] = *(const f16x8*)(bfrag + (size_t)u * 512 + l * 8);
        }
#pragma unroll
        for (int mt = 0; mt < 2; ++mt)
#pragma unroll
          for (int n4 = 0; n4 < 4; ++n4)
            acc[mt][nh * 4 + n4] = __builtin_amdgcn_mfma_f32_16x16x32_f16(
                af[mt], bf[n4], acc[mt][nh * 4 + n4], 0, 0, 0);
      }
    }
    __builtin_amdgcn_sched_barrier(0);

    // ---- cvt + write chunk c+1 into buf[(c+1)&1]
    if (c < 3) {
      unsigned char* dbuf = lds + ((c + 1) & 1) * 8192;
#pragma unroll
      for (int j2 = 0; j2 < 2; ++j2) {
        float4 x = stg[2 * j2], y = stg[2 * j2 + 1];
        f16x8 h;
        h[0] = (_Float16)x.x; h[1] = (_Float16)x.y;
        h[2] = (_Float16)x.z; h[3] = (_Float16)x.w;
        h[4] = (_Float16)y.x; h[5] = (_Float16)y.y;
        h[6] = (_Float16)y.z; h[7] = (_Float16)y.w;
        *(f16x8*)(dbuf + ((wbase + j2 * 16) ^ wswz)) = h;
      }
      __syncthreads();
    }
  }

  // ---- epilogue: tanh(qv + k) * w_att, reduce over h -> per-row scores
  float rs[8];
#pragma unroll
  for (int i = 0; i < 8; ++i) rs[i] = 0.f;
  const int hb = w * 128;
#pragma unroll
  for (int nt = 0; nt < 8; ++nt) {
    const int h = hb + nt * 16 + (l & 15);
    const float q = qv[b * 512 + h];
    const float wa = w_att[h];
#pragma unroll
    for (int mt = 0; mt < 2; ++mt)
#pragma unroll
      for (int r = 0; r < 4; ++r) {
        float x = q + acc[mt][nt][r];
        float e = __expf(x + x);
        float t = 1.f - __fdividef(2.f, e + 1.f);
        rs[mt * 4 + r] = __builtin_fmaf(t, wa, rs[mt * 4 + r]);
      }
  }
#pragma unroll
  for (int st = 1; st <= 8; st <<= 1)
#pragma unroll
    for (int i = 0; i < 8; ++i)
      rs[i] += __shfl_xor(rs[i], st, 64);

  __syncthreads();     // chunk buffers dead; LDS arrays reused below
  {
    const int idx = l & 15;     // lanes 0..7 of each col-group write
    if (idx < 8) {
      float v = rs[0];
#pragma unroll
      for (int i = 1; i < 8; ++i) v = (idx == i) ? rs[i] : v;
      // row for (mt=idx>>2, r=idx&3): 16*mt + 4*(l>>4) + r
      const int rrow = ((idx >> 2) << 4) + ((l >> 4) << 2) + (idx & 3);
      spart[w * 32 + rrow] = v;
    }
  }
  __syncthreads();
  if (tid < 32) {
    float s = spart[tid] + spart[32 + tid] + spart[64 + tid] + spart[96 + tid];
    scores[row0 + tid] = s;
    pb[tid] = s;
  }
  __syncthreads();

  // ---- tile softmax stats
  float m = -1e30f;
#pragma unroll 8
  for (int r = 0; r < 32; ++r) m = fmaxf(m, pb[r]);      // broadcast reads
  if (tid < 32) pb2[tid] = __expf(pb[tid] - m);
  __syncthreads();

  // ---- V-partial: vpart[wg][d] = sum_r pb2[r] * keys[row0+r][d]  (fp32, L3-hot)
  {
    float a0 = 0.f, a1 = 0.f, b0 = 0.f, b1 = 0.f;
    const float* kb = keys + (size_t)row0 * 512 + 2 * tid;
#pragma unroll 4
    for (int r = 0; r < 32; r += 2) {
      float2 kv = *(const float2*)(kb + (size_t)r * 512);
      float2 kw = *(const float2*)(kb + (size_t)(r + 1) * 512);
      float p0 = pb2[r], p1 = pb2[r + 1];
      a0 = __builtin_fmaf(p0, kv.x, a0);
      a1 = __builtin_fmaf(p0, kv.y, a1);
      b0 = __builtin_fmaf(p1, kw.x, b0);
      b1 = __builtin_fmaf(p1, kw.y, b1);
    }
    f16x2 o;
    o[0] = (_Float16)(a0 + b0);
    o[1] = (_Float16)(a1 + b1);
    *(f16x2*)(vpart + (size_t)wg * 512 + 2 * tid) = o;
  }
  if (tid == 0) {
    float lsum = 0.f;
#pragma unroll 8
    for (int r = 0; r < 32; ++r) lsum += pb2[r];
    stats[wg * 2] = m;
    stats[wg * 2 + 1] = lsum;
  }
}

// ---------------- C: combine 64 tiles per batch -> out, attn ----------------------
__global__ __launch_bounds__(256) void combine_kernel(
    const _Float16* __restrict__ vpart, const float* __restrict__ stats,
    const float* __restrict__ scores, float* __restrict__ out,
    float* __restrict__ attn) {
  __shared__ float smt[64], slt[64];
  const int blk = blockIdx.x, tid = threadIdx.x;
  const int b = blk & 31;
  if (tid < 64) {
    smt[tid] = stats[(b * 64 + tid) * 2];
    slt[tid] = stats[(b * 64 + tid) * 2 + 1];
  }
  __syncthreads();
  float M = -1e30f;
#pragma unroll 8
  for (int t = 0; t < 64; ++t) M = fmaxf(M, smt[t]);     // broadcast reads
  float L = 0.f;
#pragma unroll 8
  for (int t = 0; t < 64; ++t) L += __expf(smt[t] - M) * slt[t];
  const float rinv = 1.f / L;

  if (blk < 32) {
    const int d0 = 2 * tid;
    float a0 = 0.f, a1 = 0.f;
#pragma unroll 8
    for (int t = 0; t < 64; ++t) {
      float wgt = __expf(smt[t] - M);
      f16x2 vp = *(const f16x2*)(vpart + ((size_t)(b * 64 + t)) * 512 + d0);
      a0 = __builtin_fmaf(wgt, (float)vp[0], a0);
      a1 = __builtin_fmaf(wgt, (float)vp[1], a1);
    }
    out[b * 512 + d0] = a0 * rinv;
    out[b * 512 + d0 + 1] = a1 * rinv;
  } else {
#pragma unroll
    for (int j = 0; j < 8; ++j) {
      int s = j * 256 + tid;
      attn[(size_t)b * 2048 + s] = __expf(scores[(size_t)b * 2048 + s] - M) * rinv;
    }
  }
}

extern "C" void kernel_launch(void* const* d_in, const int* in_sizes, int n_in,
                              void* d_out, int out_size, void* d_ws, size_t ws_size,
                              hipStream_t stream) {
  const float* query = (const float*)d_in[0];
  const float* keys  = (const float*)d_in[1];
  const float* Wq    = (const float*)d_in[2];
  const float* Wk    = (const float*)d_in[3];
  const float* w_att = (const float*)d_in[4];
  float* out  = (float*)d_out;                  // [32,512]
  float* attn = out + 16384;                    // [32,2048]
  char* ws = (char*)d_ws;
  float*    qv     = (float*)(ws + WS_QV);
  _Float16* bfrag  = (_Float16*)(ws + WS_BF);
  float*    scores = (float*)(ws + WS_SC);
  _Float16* vpart  = (_Float16*)(ws + WS_VP);
  float*    stats  = (float*)(ws + WS_ST);

  prep_kernel<<<192, 256, 0, stream>>>(query, Wq, Wk, qv, bfrag);
  fused_kernel<<<2048, 256, 0, stream>>>(keys, bfrag, qv, w_att, scores, vpart, stats);
  combine_kernel<<<64, 256, 0, stream>>>(vpart, stats, scores, out, attn);
}